// Round 7
// baseline (14074.702 us; speedup 1.0000x reference)
//
#include <hip/hip_runtime.h>
#include <hip/hip_bf16.h>

#define B_DIM 256
#define T_DIM 512
#define WINT 64
#define IN_DIM 1024
#define HID_DIM 1024
#define BLK 16384

typedef __attribute__((ext_vector_type(8))) short bf16x8;
typedef __attribute__((ext_vector_type(4))) float f32x4;

__device__ __forceinline__ unsigned short f2bf(float v) {
  unsigned int u = __float_as_uint(v);
  unsigned int r = (u + 0x7fffu + ((u >> 16) & 1u)) >> 16;
  return (unsigned short)r;
}
__device__ __forceinline__ float bflo(unsigned u) { return __uint_as_float(u << 16); }
__device__ __forceinline__ float bfhi(unsigned u) { return __uint_as_float(u & 0xffff0000u); }

typedef __attribute__((address_space(3))) unsigned int lds_uint;
typedef const __attribute__((address_space(1))) unsigned int g_uint;
__device__ __forceinline__ void gload_lds16(const void* g, void* l) {
  __builtin_amdgcn_global_load_lds((g_uint*)g, (lds_uint*)l, 16, 0, 0);
}
// 2KB: src includes per-lane lane*16; dst is wave-uniform base.
__device__ __forceinline__ void glds2(const unsigned char* s, unsigned char* d) {
  gload_lds16(s, d);
  gload_lds16(s + 1024, d + 1024);
}

#define WAITVM(N) asm volatile("s_waitcnt vmcnt(" #N ")" ::: "memory")

// ---------------------------------------------------------------------------
// Pack W (4 gates, f32 [2048][1024]) -> bf16 swizzled blocks.
// Packed col in a 64-col block: g*16 + h_in. Block (cb, kc): [col 64][k' 128],
// byte = (col*256 + k'*2) ^ ((col&7)<<4). kc 0..7 = x rows, 8..15 = h rows.
// ---------------------------------------------------------------------------
__global__ void prep_pack_w(const float* __restrict__ Wi, const float* __restrict__ Wf,
                            const float* __restrict__ Wo, const float* __restrict__ Wc,
                            unsigned char* __restrict__ Wp) {
  const int bid = blockIdx.x;          // cb*16 + kc
  const int cb = bid >> 4, kc = bid & 15;
  const int tid = threadIdx.x;
  const int col = tid & 63;
  const int g = col >> 4, h_in = col & 15;
  const int kq = tid >> 6;
  const float* W = (g == 0) ? Wi : (g == 1) ? Wf : (g == 2) ? Wo : Wc;
  const float* src = W + (size_t)(kc * 128 + kq * 32) * HID_DIM + cb * 16 + h_in;
  unsigned char* dst = Wp + (size_t)bid * BLK;
  const unsigned int xo = (unsigned int)((col & 7) << 4);
#pragma unroll
  for (int b4 = 0; b4 < 4; ++b4) {
    unsigned short u[8];
#pragma unroll
    for (int j = 0; j < 8; ++j)
      u[j] = f2bf(src[(size_t)(b4 * 8 + j) * HID_DIM]);
    uint4 pk;
    pk.x = (unsigned)u[0] | ((unsigned)u[1] << 16);
    pk.y = (unsigned)u[2] | ((unsigned)u[3] << 16);
    pk.z = (unsigned)u[4] | ((unsigned)u[5] << 16);
    pk.w = (unsigned)u[6] | ((unsigned)u[7] << 16);
    unsigned int byte = ((unsigned int)(col * 256 + kq * 64 + b4 * 16)) ^ xo;
    *(uint4*)(dst + byte) = pk;
  }
}

__global__ void prep_bias(const float* __restrict__ bi, const float* __restrict__ bf_,
                          const float* __restrict__ bo, const float* __restrict__ bc,
                          float* __restrict__ bp) {
  int p = blockIdx.x * 256 + threadIdx.x;  // 0..4095
  int cbb = p >> 6, col = p & 63, g = col >> 4, h_in = col & 15;
  const float* b = (g == 0) ? bi : (g == 1) ? bf_ : (g == 2) ? bo : bc;
  bp[p] = b[cbb * 16 + h_in];
}

// Pack one 64-step window of x -> bf16 swizzled blocks (tw,mb,kc) = bid.
__global__ void prep_pack_x_win(const float* __restrict__ x,
                                unsigned char* __restrict__ xpw, int t0) {
  const int bid = blockIdx.x;               // (tw*4+mb)*8+kc, 2048 blocks
  const int kc = bid & 7, mb = (bid >> 3) & 3, tw = bid >> 5;
  const int tid = threadIdx.x;
  const int row = tid >> 2, kseg = tid & 3;
  const float* src = x + ((size_t)(mb * 64 + row) * T_DIM + (t0 + tw)) * IN_DIM +
                     kc * 128 + kseg * 32;
  unsigned char* dst = xpw + (size_t)bid * BLK;
  const unsigned int xo = (unsigned)((row & 7) << 4);
#pragma unroll
  for (int c4 = 0; c4 < 4; ++c4) {
    float4 f0 = *(const float4*)(src + c4 * 8);
    float4 f1 = *(const float4*)(src + c4 * 8 + 4);
    uint4 pk;
    pk.x = (unsigned)f2bf(f0.x) | ((unsigned)f2bf(f0.y) << 16);
    pk.y = (unsigned)f2bf(f0.z) | ((unsigned)f2bf(f0.w) << 16);
    pk.z = (unsigned)f2bf(f1.x) | ((unsigned)f2bf(f1.y) << 16);
    pk.w = (unsigned)f2bf(f1.z) | ((unsigned)f2bf(f1.w) << 16);
    *(uint4*)(dst + (((unsigned)(row * 256 + kseg * 64 + c4 * 16)) ^ xo)) = pk;
  }
}

// ---------------------------------------------------------------------------
// Bulk Gx for one window (unchanged; proven).
// ---------------------------------------------------------------------------
__global__ __launch_bounds__(512, 2) void bulk_gx(
    const unsigned char* __restrict__ xpw, const unsigned char* __restrict__ Wq,
    unsigned char* __restrict__ gxw) {
  extern __shared__ unsigned char ring[];  // 4 x 16KB; gates overlays buf0
  const int wg = blockIdx.x;
  const int cb = wg & 63, mb = (wg >> 6) & 3, tg = wg >> 8;
  const int tid = threadIdx.x, lane = tid & 63, w = tid >> 6;
  const int rg = w & 1, cg = (w >> 1) & 1, kh = w >> 2;
  const int fr = lane & 15;
  const unsigned koff2 = (unsigned)((lane >> 4) << 4);
  const int rsub = (lane >> 4) * 4;
  const int cl = cg * 32 + fr;  // per-cbf: + cbf*16

  bf16x8 Breg[4][2][4];
#pragma unroll
  for (int ci = 0; ci < 4; ++ci)
#pragma unroll
    for (int cbf = 0; cbf < 2; ++cbf)
#pragma unroll
      for (int ks = 0; ks < 4; ++ks) {
        const unsigned c2 = (unsigned)(cl + cbf * 16);
        Breg[ci][cbf][ks] = *(const bf16x8*)(
            Wq + ((size_t)(cb * 16 + kh * 4 + ci) << 14) +
            ((c2 * 256 + (unsigned)ks * 64 + koff2) ^ ((c2 & 7) << 4)));
      }

  float* gates = (float*)ring;
  unsigned char* dstb = ring + w * 2048;

#pragma unroll 1
  for (int i = 0; i < 16; ++i) {
    const int tl = tg * 16 + i;
    const unsigned char* xA =
        xpw + ((size_t)((tl * 4 + mb) * 8)) * BLK + w * 2048 + lane * 16;
    f32x4 acc[2][2] = {{{0.f,0.f,0.f,0.f},{0.f,0.f,0.f,0.f}},
                       {{0.f,0.f,0.f,0.f},{0.f,0.f,0.f,0.f}}};
#pragma unroll
    for (int c = 0; c < 4; ++c) glds2(xA + (size_t)c * BLK, dstb + c * 16384);
#pragma unroll
    for (int kc = 0; kc < 8; ++kc) {
      if (kc <= 4) WAITVM(6);
      else if (kc == 5) WAITVM(4);
      else if (kc == 6) WAITVM(2);
      else WAITVM(0);
      __builtin_amdgcn_s_barrier();
      if ((kc >> 2) == kh) {
        const unsigned char* Ab = ring + (kc & 3) * 16384;
#pragma unroll
        for (int ks = 0; ks < 4; ++ks) {
          const unsigned r0 = (unsigned)(rg * 32 + fr), r1 = r0 + 16;
          const unsigned kb = (unsigned)ks * 64 + koff2;
          bf16x8 a0 = *(const bf16x8*)(Ab + ((r0 * 256 + kb) ^ ((r0 & 7) << 4)));
          bf16x8 a1 = *(const bf16x8*)(Ab + ((r1 * 256 + kb) ^ ((r1 & 7) << 4)));
#pragma unroll
          for (int cbf = 0; cbf < 2; ++cbf) {
            acc[0][cbf] = __builtin_amdgcn_mfma_f32_16x16x32_bf16(
                a0, Breg[kc & 3][cbf][ks], acc[0][cbf], 0, 0, 0);
            acc[1][cbf] = __builtin_amdgcn_mfma_f32_16x16x32_bf16(
                a1, Breg[kc & 3][cbf][ks], acc[1][cbf], 0, 0, 0);
          }
        }
      }
      __builtin_amdgcn_s_barrier();
      if (kc + 4 < 8) glds2(xA + (size_t)(kc + 4) * BLK, dstb + ((kc + 4) & 3) * 16384);
    }
    if (kh == 0) {
#pragma unroll
      for (int rb = 0; rb < 2; ++rb)
#pragma unroll
        for (int cbf = 0; cbf < 2; ++cbf)
#pragma unroll
          for (int j = 0; j < 4; ++j)
            gates[(rg * 32 + rb * 16 + rsub + j) * 65 + cg * 32 + cbf * 16 + fr] =
                acc[rb][cbf][j];
    }
    __syncthreads();
    if (kh == 1) {
#pragma unroll
      for (int rb = 0; rb < 2; ++rb)
#pragma unroll
        for (int cbf = 0; cbf < 2; ++cbf)
#pragma unroll
          for (int j = 0; j < 4; ++j)
            gates[(rg * 32 + rb * 16 + rsub + j) * 65 + cg * 32 + cbf * 16 + fr] +=
                acc[rb][cbf][j];
    }
    __syncthreads();
    {  // pack bf16 in epilogue-thread layout: uint4 at tid*16
      const int erow = tid & 63, hb2 = (tid >> 6) * 2;
      uint4 pk;
      unsigned u[4];
#pragma unroll
      for (int g = 0; g < 4; ++g) {
        float lo = gates[erow * 65 + g * 16 + hb2];
        float hi = gates[erow * 65 + g * 16 + hb2 + 1];
        u[g] = (unsigned)f2bf(lo) | ((unsigned)f2bf(hi) << 16);
      }
      pk.x = u[0]; pk.y = u[1]; pk.z = u[2]; pk.w = u[3];
      *(uint4*)(gxw + ((size_t)((tl * 4 + mb) * 64 + cb)) * 8192 + (size_t)tid * 16) = pk;
    }
    __syncthreads();
  }
}

// ---------------------------------------------------------------------------
// Sequential window kernel v3. 256 WG (1/CU) x 512 thr (8 waves).
// Split-K wave layout: wave (cg=w&3, kh=w>>2) owns cols cg*16..+15 and
// K-chunks kh*4..+3 -> Breg[4][4] = 64 VGPR, truly register-resident.
// Two parallel gates buffers (kh=0 -> gates0 @ring, kh=1 -> gates1 @+32KB),
// epilogue sums them. Flags: tid0 read-only spin + acquire (round-6 proven).
// ---------------------------------------------------------------------------
__global__ __launch_bounds__(512, 1) void lstm_seq(
    const unsigned char* __restrict__ gxw, const unsigned char* __restrict__ Wq,
    const float* __restrict__ bp, unsigned char* hring,
    unsigned int* prodCnt, float* cst, float* __restrict__ out, int t0) {
  extern __shared__ unsigned char ring[];  // 8 x 16KB chunk bufs
  const int wg = blockIdx.x, mb = wg >> 6, cb = wg & 63;
  const int tid = threadIdx.x, lane = tid & 63, w = tid >> 6;
  const int cg = w & 3, kh = w >> 2;   // cols cg*16..+15, chunks kh*4..+3
  const int fr = lane & 15;
  const unsigned koff2 = (unsigned)((lane >> 4) << 4);
  const int rsub = (lane >> 4) * 4;
  const int cl = cg * 16 + fr;

  bf16x8 Breg[4][4];  // Wh slice: block cb*16 + 8 + kh*4 + kcl, col cl
#pragma unroll
  for (int kcl = 0; kcl < 4; ++kcl)
#pragma unroll
    for (int ks = 0; ks < 4; ++ks)
      Breg[kcl][ks] = *(const bf16x8*)(
          Wq + ((size_t)(cb * 16 + 8 + kh * 4 + kcl) << 14) +
          (((unsigned)cl * 256 + (unsigned)ks * 64 + koff2) ^ ((unsigned)((cl & 7) << 4))));
#pragma unroll
  for (int kcl = 0; kcl < 4; ++kcl)
#pragma unroll
    for (int ks = 0; ks < 4; ++ks)
      asm volatile("" : "+v"(Breg[kcl][ks]));

  const int erow = tid & 63, hb2 = (tid >> 6) * 2;
  const size_t gidx = (size_t)(mb * 64 + erow) * HID_DIM + cb * 16 + hb2;
  float bI[2], bF[2], bO[2], bG[2];
#pragma unroll
  for (int j = 0; j < 2; ++j) {
    bI[j] = bp[cb * 64 + hb2 + j];
    bF[j] = bp[cb * 64 + 16 + hb2 + j];
    bO[j] = bp[cb * 64 + 32 + hb2 + j];
    bG[j] = bp[cb * 64 + 48 + hb2 + j];
  }
  float cr[2] = {0.f, 0.f};
  if (t0 > 0) { float2 c2v = *(const float2*)(cst + gidx); cr[0] = c2v.x; cr[1] = c2v.y; }

  float* gates0 = (float*)ring;            // 64x65 f32 overlay on bufs 0-1
  float* gates1 = (float*)(ring + 32768);  // 64x65 f32 overlay on bufs 2-3

#pragma unroll 1
  for (int tt = 0; tt < WINT; ++tt) {
    const int t = t0 + tt;
    // keep Wh pinned in registers across the loop (no remat)
#pragma unroll
    for (int kcl = 0; kcl < 4; ++kcl)
#pragma unroll
      for (int ks = 0; ks < 4; ++ks)
        asm volatile("" : "+v"(Breg[kcl][ks]));
    // Gx prefetch (stable data from the bulk kernel): issue before the spin
    uint4 gxv = *(const uint4*)(gxw + ((size_t)((tt * 4 + mb) * 64 + cb)) * 8192 +
                                (size_t)tid * 16);
    f32x4 acc[4] = {{0.f,0.f,0.f,0.f},{0.f,0.f,0.f,0.f},
                    {0.f,0.f,0.f,0.f},{0.f,0.f,0.f,0.f}};
    if (t > 0) {
      if (tid == 0) {  // read-only spin: no ownership ping-pong
        while (__hip_atomic_load(&prodCnt[(t - 1) * 4 + mb], __ATOMIC_RELAXED,
                                 __HIP_MEMORY_SCOPE_AGENT) < 64u)
          __builtin_amdgcn_s_sleep(4);
        (void)__hip_atomic_load(&prodCnt[(t - 1) * 4 + mb], __ATOMIC_ACQUIRE,
                                __HIP_MEMORY_SCOPE_AGENT);  // L1/L2 invalidate
      }
      __syncthreads();
      const unsigned char* hA = hring + (size_t)((t + 2) % 3) * 524288 +
                                (size_t)(mb * 8) * BLK + w * 2048 + lane * 16;
#pragma unroll
      for (int c = 0; c < 8; ++c)  // all 8 chunks in flight
        glds2(hA + (size_t)c * BLK, ring + c * 16384 + w * 2048);
#pragma unroll
      for (int kc = 0; kc < 8; ++kc) {
        if (kc == 0) WAITVM(14);
        else if (kc == 1) WAITVM(12);
        else if (kc == 2) WAITVM(10);
        else if (kc == 3) WAITVM(8);
        else if (kc == 4) WAITVM(6);
        else if (kc == 5) WAITVM(4);
        else if (kc == 6) WAITVM(2);
        else WAITVM(0);
        __builtin_amdgcn_s_barrier();
        if ((kc >> 2) == kh) {
          const int kcl = kc & 3;
          const unsigned char* Ab = ring + kc * 16384;
#pragma unroll
          for (int ks = 0; ks < 4; ++ks) {
            const unsigned kb = (unsigned)ks * 64 + koff2;
#pragma unroll
            for (int rb = 0; rb < 4; ++rb) {
              const unsigned r0 = (unsigned)(rb * 16 + fr);
              bf16x8 a0 = *(const bf16x8*)(Ab + ((r0 * 256 + kb) ^ ((r0 & 7) << 4)));
              acc[rb] = __builtin_amdgcn_mfma_f32_16x16x32_bf16(
                  a0, Breg[kcl][ks], acc[rb], 0, 0, 0);
            }
          }
        }
      }
    }
    // parallel exchange: kh=0 -> gates0, kh=1 -> gates1 (no cross-dependency)
    {
      float* gx_ = (kh == 0) ? gates0 : gates1;
#pragma unroll
      for (int rb = 0; rb < 4; ++rb)
#pragma unroll
        for (int j = 0; j < 4; ++j)
          gx_[(rb * 16 + rsub + j) * 65 + cg * 16 + fr] = acc[rb][j];
    }
    __syncthreads();
    // epilogue
    float hv[2];
    {
      unsigned gu0 = gxv.x, gu1 = gxv.y, gu2 = gxv.z, gu3 = gxv.w;
#pragma unroll
      for (int j = 0; j < 2; ++j) {
        int hc = hb2 + j;
        float gx0 = j ? bfhi(gu0) : bflo(gu0);
        float gx1 = j ? bfhi(gu1) : bflo(gu1);
        float gx2 = j ? bfhi(gu2) : bflo(gu2);
        float gx3 = j ? bfhi(gu3) : bflo(gu3);
        float pi = gates0[erow * 65 + hc]      + gates1[erow * 65 + hc]      + bI[j] + gx0;
        float pf = gates0[erow * 65 + 16 + hc] + gates1[erow * 65 + 16 + hc] + bF[j] + gx1;
        float po = gates0[erow * 65 + 32 + hc] + gates1[erow * 65 + 32 + hc] + bO[j] + gx2;
        float pg = gates0[erow * 65 + 48 + hc] + gates1[erow * 65 + 48 + hc] + bG[j] + gx3;
        float ig = 1.f / (1.f + __expf(-pi));
        float fg = 1.f / (1.f + __expf(-pf));
        float og = 1.f / (1.f + __expf(-po));
        float gg = 1.f - 2.f / (1.f + __expf(2.f * pg));  // tanh
        float cn = fg * cr[j] + ig * gg;
        cr[j] = cn;
        hv[j] = og * (1.f - 2.f / (1.f + __expf(2.f * cn)));
      }
    }
    if (t < T_DIM - 1) {  // store h_t bf16-pair into slot t%3, swizzled
      int hcg = cb * 16 + hb2;
      int kc2 = hcg >> 7, kp = hcg & 127;
      unsigned byte = ((unsigned)(erow * 256 + kp * 2)) ^ ((unsigned)((erow & 7) << 4));
      unsigned pk = (unsigned)f2bf(hv[0]) | ((unsigned)f2bf(hv[1]) << 16);
      unsigned int* hd = (unsigned int*)(hring + (size_t)(t % 3) * 524288 +
                                         (size_t)(mb * 8 + kc2) * BLK + byte);
      __hip_atomic_store(hd, pk, __ATOMIC_RELAXED, __HIP_MEMORY_SCOPE_AGENT);
    }
    WAITVM(0);
    __syncthreads();  // gates reads done + h-store drained before flag / reuse
    if (tid == 0 && t < T_DIM - 1)
      __hip_atomic_fetch_add(&prodCnt[t * 4 + mb], 1u, __ATOMIC_RELEASE,
                             __HIP_MEMORY_SCOPE_AGENT);
    if (t == T_DIM - 1) {
      *(float2*)(out + gidx) = make_float2(hv[0], hv[1]);
      *(float2*)(out + (size_t)B_DIM * HID_DIM + gidx) = make_float2(cr[0], cr[1]);
    }
  }
  if (t0 + WINT < T_DIM) *(float2*)(cst + gidx) = make_float2(cr[0], cr[1]);
}

extern "C" void kernel_launch(void* const* d_in, const int* in_sizes, int n_in,
                              void* d_out, int out_size, void* d_ws, size_t ws_size,
                              hipStream_t stream) {
  (void)in_sizes; (void)n_in; (void)out_size;
  const float* x   = (const float*)d_in[0];
  const float* Wf_ = (const float*)d_in[1];
  const float* bf_ = (const float*)d_in[2];
  const float* Wi_ = (const float*)d_in[3];
  const float* bi_ = (const float*)d_in[4];
  const float* Wo_ = (const float*)d_in[5];
  const float* bo_ = (const float*)d_in[6];
  const float* Wc_ = (const float*)d_in[7];
  const float* bc_ = (const float*)d_in[8];
  float* out = (float*)d_out;
  unsigned char* ws = (unsigned char*)d_ws;

  unsigned char* Wp = ws;
  size_t off = 16777216;
  float* bp = (float*)(ws + off);                    off += 16384;
  unsigned int* prodCnt = (unsigned int*)(ws + off); off += 8192;
  unsigned int* consCnt = (unsigned int*)(ws + off); off += 8192;  // unused
  (void)consCnt;
  unsigned char* hring = ws + off;                   off += 3 * 524288;
  float* cst = (float*)(ws + off);                   off += 1048576;
  unsigned char* xpw = ws + off;                     off += (size_t)2048 * BLK;   // 33.5 MB
  unsigned char* gxw = ws + off;                     off += (size_t)WINT * 256 * 8192;  // 134 MB
  if (ws_size < off) return;  // proven available

  prep_pack_w<<<1024, 256, 0, stream>>>(Wi_, Wf_, Wo_, Wc_, Wp);
  prep_bias<<<16, 256, 0, stream>>>(bi_, bf_, bo_, bc_, bp);
  hipMemsetAsync(prodCnt, 0, 16384, stream);

  hipFuncSetAttribute((const void*)bulk_gx,
                      hipFuncAttributeMaxDynamicSharedMemorySize, 65536);
  hipFuncSetAttribute((const void*)lstm_seq,
                      hipFuncAttributeMaxDynamicSharedMemorySize, 131072);

  for (int t0 = 0; t0 < T_DIM; t0 += WINT) {
    prep_pack_x_win<<<2048, 256, 0, stream>>>(x, xpw, t0);
    bulk_gx<<<1024, 512, 65536, stream>>>(xpw, Wp, gxw);
    const unsigned char* a_gx = gxw;
    const unsigned char* a_wp = Wp;
    const float* a_bp = bp;
    unsigned char* a_hr = hring;
    unsigned int* a_pc = prodCnt;
    float* a_cs = cst;
    float* a_out = out;
    int a_t0 = t0;
    void* args[] = {&a_gx, &a_wp, &a_bp, &a_hr, &a_pc, &a_cs, &a_out, &a_t0};
    hipLaunchCooperativeKernel((const void*)lstm_seq, dim3(256), dim3(512),
                               args, 131072u, stream);
  }
}

// Round 8
// 9463.373 us; speedup vs baseline: 1.4873x; 1.4873x over previous
//
#include <hip/hip_runtime.h>
#include <hip/hip_bf16.h>

#define B_DIM 256
#define T_DIM 512
#define WINT 64
#define IN_DIM 1024
#define HID_DIM 1024
#define BLK 16384

typedef __attribute__((ext_vector_type(8))) short bf16x8;
typedef __attribute__((ext_vector_type(4))) float f32x4;

__device__ __forceinline__ unsigned short f2bf(float v) {
  unsigned int u = __float_as_uint(v);
  unsigned int r = (u + 0x7fffu + ((u >> 16) & 1u)) >> 16;
  return (unsigned short)r;
}
__device__ __forceinline__ float bflo(unsigned u) { return __uint_as_float(u << 16); }
__device__ __forceinline__ float bfhi(unsigned u) { return __uint_as_float(u & 0xffff0000u); }

typedef __attribute__((address_space(3))) unsigned int lds_uint;
typedef const __attribute__((address_space(1))) unsigned int g_uint;
__device__ __forceinline__ void gload_lds16(const void* g, void* l) {
  __builtin_amdgcn_global_load_lds((g_uint*)g, (lds_uint*)l, 16, 0, 0);
}
// 2KB: src includes per-lane offset; dst is wave-uniform base.
__device__ __forceinline__ void glds2(const unsigned char* s, unsigned char* d) {
  gload_lds16(s, d);
  gload_lds16(s + 1024, d + 1024);
}

#define WAITVM(N) asm volatile("s_waitcnt vmcnt(" #N ")" ::: "memory")

// ---------------------------------------------------------------------------
// Pack W (4 gates, f32 [2048][1024]) -> bf16 swizzled blocks.
// Packed col in a 64-col block: g*16 + h_in. Block (cb, kc): [col 64][k' 128],
// byte = (col*256 + k'*2) ^ ((col&7)<<4). kc 0..7 = x rows, 8..15 = h rows.
// ---------------------------------------------------------------------------
__global__ void prep_pack_w(const float* __restrict__ Wi, const float* __restrict__ Wf,
                            const float* __restrict__ Wo, const float* __restrict__ Wc,
                            unsigned char* __restrict__ Wp) {
  const int bid = blockIdx.x;          // cb*16 + kc
  const int cb = bid >> 4, kc = bid & 15;
  const int tid = threadIdx.x;
  const int col = tid & 63;
  const int g = col >> 4, h_in = col & 15;
  const int kq = tid >> 6;
  const float* W = (g == 0) ? Wi : (g == 1) ? Wf : (g == 2) ? Wo : Wc;
  const float* src = W + (size_t)(kc * 128 + kq * 32) * HID_DIM + cb * 16 + h_in;
  unsigned char* dst = Wp + (size_t)bid * BLK;
  const unsigned int xo = (unsigned int)((col & 7) << 4);
#pragma unroll
  for (int b4 = 0; b4 < 4; ++b4) {
    unsigned short u[8];
#pragma unroll
    for (int j = 0; j < 8; ++j)
      u[j] = f2bf(src[(size_t)(b4 * 8 + j) * HID_DIM]);
    uint4 pk;
    pk.x = (unsigned)u[0] | ((unsigned)u[1] << 16);
    pk.y = (unsigned)u[2] | ((unsigned)u[3] << 16);
    pk.z = (unsigned)u[4] | ((unsigned)u[5] << 16);
    pk.w = (unsigned)u[6] | ((unsigned)u[7] << 16);
    unsigned int byte = ((unsigned int)(col * 256 + kq * 64 + b4 * 16)) ^ xo;
    *(uint4*)(dst + byte) = pk;
  }
}

__global__ void prep_bias(const float* __restrict__ bi, const float* __restrict__ bf_,
                          const float* __restrict__ bo, const float* __restrict__ bc,
                          float* __restrict__ bp) {
  int p = blockIdx.x * 256 + threadIdx.x;  // 0..4095
  int cbb = p >> 6, col = p & 63, g = col >> 4, h_in = col & 15;
  const float* b = (g == 0) ? bi : (g == 1) ? bf_ : (g == 2) ? bo : bc;
  bp[p] = b[cbb * 16 + h_in];
}

// Pack one 64-step window of x -> bf16 swizzled blocks (tw,mb,kc) = bid.
__global__ void prep_pack_x_win(const float* __restrict__ x,
                                unsigned char* __restrict__ xpw, int t0) {
  const int bid = blockIdx.x;               // (tw*4+mb)*8+kc, 2048 blocks
  const int kc = bid & 7, mb = (bid >> 3) & 3, tw = bid >> 5;
  const int tid = threadIdx.x;
  const int row = tid >> 2, kseg = tid & 3;
  const float* src = x + ((size_t)(mb * 64 + row) * T_DIM + (t0 + tw)) * IN_DIM +
                     kc * 128 + kseg * 32;
  unsigned char* dst = xpw + (size_t)bid * BLK;
  const unsigned int xo = (unsigned)((row & 7) << 4);
#pragma unroll
  for (int c4 = 0; c4 < 4; ++c4) {
    float4 f0 = *(const float4*)(src + c4 * 8);
    float4 f1 = *(const float4*)(src + c4 * 8 + 4);
    uint4 pk;
    pk.x = (unsigned)f2bf(f0.x) | ((unsigned)f2bf(f0.y) << 16);
    pk.y = (unsigned)f2bf(f0.z) | ((unsigned)f2bf(f0.w) << 16);
    pk.z = (unsigned)f2bf(f1.x) | ((unsigned)f2bf(f1.y) << 16);
    pk.w = (unsigned)f2bf(f1.z) | ((unsigned)f2bf(f1.w) << 16);
    *(uint4*)(dst + (((unsigned)(row * 256 + kseg * 64 + c4 * 16)) ^ xo)) = pk;
  }
}

// ---------------------------------------------------------------------------
// Bulk Gx for one window (unchanged; proven).
// ---------------------------------------------------------------------------
__global__ __launch_bounds__(512, 2) void bulk_gx(
    const unsigned char* __restrict__ xpw, const unsigned char* __restrict__ Wq,
    unsigned char* __restrict__ gxw) {
  extern __shared__ unsigned char ring[];  // 4 x 16KB; gates overlays buf0
  const int wg = blockIdx.x;
  const int cb = wg & 63, mb = (wg >> 6) & 3, tg = wg >> 8;
  const int tid = threadIdx.x, lane = tid & 63, w = tid >> 6;
  const int rg = w & 1, cg = (w >> 1) & 1, kh = w >> 2;
  const int fr = lane & 15;
  const unsigned koff2 = (unsigned)((lane >> 4) << 4);
  const int rsub = (lane >> 4) * 4;
  const int cl = cg * 32 + fr;  // per-cbf: + cbf*16

  bf16x8 Breg[4][2][4];
#pragma unroll
  for (int ci = 0; ci < 4; ++ci)
#pragma unroll
    for (int cbf = 0; cbf < 2; ++cbf)
#pragma unroll
      for (int ks = 0; ks < 4; ++ks) {
        const unsigned c2 = (unsigned)(cl + cbf * 16);
        Breg[ci][cbf][ks] = *(const bf16x8*)(
            Wq + ((size_t)(cb * 16 + kh * 4 + ci) << 14) +
            ((c2 * 256 + (unsigned)ks * 64 + koff2) ^ ((c2 & 7) << 4)));
      }

  float* gates = (float*)ring;
  unsigned char* dstb = ring + w * 2048;

#pragma unroll 1
  for (int i = 0; i < 16; ++i) {
    const int tl = tg * 16 + i;
    const unsigned char* xA =
        xpw + ((size_t)((tl * 4 + mb) * 8)) * BLK + w * 2048 + lane * 16;
    f32x4 acc[2][2] = {{{0.f,0.f,0.f,0.f},{0.f,0.f,0.f,0.f}},
                       {{0.f,0.f,0.f,0.f},{0.f,0.f,0.f,0.f}}};
#pragma unroll
    for (int c = 0; c < 4; ++c) glds2(xA + (size_t)c * BLK, dstb + c * 16384);
#pragma unroll
    for (int kc = 0; kc < 8; ++kc) {
      if (kc <= 4) WAITVM(6);
      else if (kc == 5) WAITVM(4);
      else if (kc == 6) WAITVM(2);
      else WAITVM(0);
      __builtin_amdgcn_s_barrier();
      if ((kc >> 2) == kh) {
        const unsigned char* Ab = ring + (kc & 3) * 16384;
#pragma unroll
        for (int ks = 0; ks < 4; ++ks) {
          const unsigned r0 = (unsigned)(rg * 32 + fr), r1 = r0 + 16;
          const unsigned kb = (unsigned)ks * 64 + koff2;
          bf16x8 a0 = *(const bf16x8*)(Ab + ((r0 * 256 + kb) ^ ((r0 & 7) << 4)));
          bf16x8 a1 = *(const bf16x8*)(Ab + ((r1 * 256 + kb) ^ ((r1 & 7) << 4)));
#pragma unroll
          for (int cbf = 0; cbf < 2; ++cbf) {
            acc[0][cbf] = __builtin_amdgcn_mfma_f32_16x16x32_bf16(
                a0, Breg[kc & 3][cbf][ks], acc[0][cbf], 0, 0, 0);
            acc[1][cbf] = __builtin_amdgcn_mfma_f32_16x16x32_bf16(
                a1, Breg[kc & 3][cbf][ks], acc[1][cbf], 0, 0, 0);
          }
        }
      }
      __builtin_amdgcn_s_barrier();
      if (kc + 4 < 8) glds2(xA + (size_t)(kc + 4) * BLK, dstb + ((kc + 4) & 3) * 16384);
    }
    if (kh == 0) {
#pragma unroll
      for (int rb = 0; rb < 2; ++rb)
#pragma unroll
        for (int cbf = 0; cbf < 2; ++cbf)
#pragma unroll
          for (int j = 0; j < 4; ++j)
            gates[(rg * 32 + rb * 16 + rsub + j) * 65 + cg * 32 + cbf * 16 + fr] =
                acc[rb][cbf][j];
    }
    __syncthreads();
    if (kh == 1) {
#pragma unroll
      for (int rb = 0; rb < 2; ++rb)
#pragma unroll
        for (int cbf = 0; cbf < 2; ++cbf)
#pragma unroll
          for (int j = 0; j < 4; ++j)
            gates[(rg * 32 + rb * 16 + rsub + j) * 65 + cg * 32 + cbf * 16 + fr] +=
                acc[rb][cbf][j];
    }
    __syncthreads();
    {  // pack bf16 in epilogue-thread layout: uint4 at tid*16
      const int erow = tid & 63, hb2 = (tid >> 6) * 2;
      uint4 pk;
      unsigned u[4];
#pragma unroll
      for (int g = 0; g < 4; ++g) {
        float lo = gates[erow * 65 + g * 16 + hb2];
        float hi = gates[erow * 65 + g * 16 + hb2 + 1];
        u[g] = (unsigned)f2bf(lo) | ((unsigned)f2bf(hi) << 16);
      }
      pk.x = u[0]; pk.y = u[1]; pk.z = u[2]; pk.w = u[3];
      *(uint4*)(gxw + ((size_t)((tl * 4 + mb) * 64 + cb)) * 8192 + (size_t)tid * 16) = pk;
    }
    __syncthreads();
  }
}

// ---------------------------------------------------------------------------
// Sequential window kernel v4. Identical to v3 EXCEPT the flag mechanism:
// per-WG flag slots (release STORE of t+1 by each producer; consumer wave 0
// polls all 64 slots in parallel with relaxed loads + __all ballot). No RMW
// -> no 64-way exclusive-ownership serialization on one line.
// ---------------------------------------------------------------------------
__global__ __launch_bounds__(512, 1) void lstm_seq(
    const unsigned char* __restrict__ gxw, const unsigned char* __restrict__ Wq,
    const float* __restrict__ bp, unsigned char* hring,
    unsigned int* flags, float* cst, float* __restrict__ out, int t0) {
  extern __shared__ unsigned char ring[];  // 8 x 16KB chunk bufs
  const int wg = blockIdx.x, mb = wg >> 6, cb = wg & 63;
  const int tid = threadIdx.x, lane = tid & 63, w = tid >> 6;
  const int cg = w & 3, kh = w >> 2;   // cols cg*16..+15, chunks kh*4..+3
  const int fr = lane & 15;
  const unsigned koff2 = (unsigned)((lane >> 4) << 4);
  const int rsub = (lane >> 4) * 4;
  const int cl = cg * 16 + fr;

  bf16x8 Breg[4][4];  // Wh slice: block cb*16 + 8 + kh*4 + kcl, col cl
#pragma unroll
  for (int kcl = 0; kcl < 4; ++kcl)
#pragma unroll
    for (int ks = 0; ks < 4; ++ks)
      Breg[kcl][ks] = *(const bf16x8*)(
          Wq + ((size_t)(cb * 16 + 8 + kh * 4 + kcl) << 14) +
          (((unsigned)cl * 256 + (unsigned)ks * 64 + koff2) ^ ((unsigned)((cl & 7) << 4))));
#pragma unroll
  for (int kcl = 0; kcl < 4; ++kcl)
#pragma unroll
    for (int ks = 0; ks < 4; ++ks)
      asm volatile("" : "+v"(Breg[kcl][ks]));

  const int erow = tid & 63, hb2 = (tid >> 6) * 2;
  const size_t gidx = (size_t)(mb * 64 + erow) * HID_DIM + cb * 16 + hb2;
  float bI[2], bF[2], bO[2], bG[2];
#pragma unroll
  for (int j = 0; j < 2; ++j) {
    bI[j] = bp[cb * 64 + hb2 + j];
    bF[j] = bp[cb * 64 + 16 + hb2 + j];
    bO[j] = bp[cb * 64 + 32 + hb2 + j];
    bG[j] = bp[cb * 64 + 48 + hb2 + j];
  }
  float cr[2] = {0.f, 0.f};
  if (t0 > 0) { float2 c2v = *(const float2*)(cst + gidx); cr[0] = c2v.x; cr[1] = c2v.y; }

  float* gates0 = (float*)ring;            // 64x65 f32 overlay on bufs 0-1
  float* gates1 = (float*)(ring + 32768);  // 64x65 f32 overlay on bufs 2-3

#pragma unroll 1
  for (int tt = 0; tt < WINT; ++tt) {
    const int t = t0 + tt;
#pragma unroll
    for (int kcl = 0; kcl < 4; ++kcl)
#pragma unroll
      for (int ks = 0; ks < 4; ++ks)
        asm volatile("" : "+v"(Breg[kcl][ks]));
    // Gx prefetch (stable data from the bulk kernel): issue before the spin
    uint4 gxv = *(const uint4*)(gxw + ((size_t)((tt * 4 + mb) * 64 + cb)) * 8192 +
                                (size_t)tid * 16);
    f32x4 acc[4] = {{0.f,0.f,0.f,0.f},{0.f,0.f,0.f,0.f},
                    {0.f,0.f,0.f,0.f},{0.f,0.f,0.f,0.f}};
    if (t > 0) {
      if (w == 0) {  // wave 0: 64 lanes poll 64 per-WG flags in parallel
        unsigned int* fl = &flags[mb * 64 + lane];
        while (!__all(__hip_atomic_load(fl, __ATOMIC_RELAXED,
                                        __HIP_MEMORY_SCOPE_AGENT) >= (unsigned)t))
          __builtin_amdgcn_s_sleep(2);
        (void)__hip_atomic_load(fl, __ATOMIC_ACQUIRE,
                                __HIP_MEMORY_SCOPE_AGENT);  // L1/L2 invalidate
      }
      __syncthreads();
      const unsigned char* hA = hring + (size_t)((t + 2) % 3) * 524288 +
                                (size_t)(mb * 8) * BLK + w * 2048 + lane * 16;
#pragma unroll
      for (int c = 0; c < 8; ++c)  // all 8 chunks in flight
        glds2(hA + (size_t)c * BLK, ring + c * 16384 + w * 2048);
#pragma unroll
      for (int kc = 0; kc < 8; ++kc) {
        if (kc == 0) WAITVM(14);
        else if (kc == 1) WAITVM(12);
        else if (kc == 2) WAITVM(10);
        else if (kc == 3) WAITVM(8);
        else if (kc == 4) WAITVM(6);
        else if (kc == 5) WAITVM(4);
        else if (kc == 6) WAITVM(2);
        else WAITVM(0);
        __builtin_amdgcn_s_barrier();
        if ((kc >> 2) == kh) {
          const int kcl = kc & 3;
          const unsigned char* Ab = ring + kc * 16384;
#pragma unroll
          for (int ks = 0; ks < 4; ++ks) {
            const unsigned kb = (unsigned)ks * 64 + koff2;
#pragma unroll
            for (int rb = 0; rb < 4; ++rb) {
              const unsigned r0 = (unsigned)(rb * 16 + fr);
              bf16x8 a0 = *(const bf16x8*)(Ab + ((r0 * 256 + kb) ^ ((r0 & 7) << 4)));
              acc[rb] = __builtin_amdgcn_mfma_f32_16x16x32_bf16(
                  a0, Breg[kcl][ks], acc[rb], 0, 0, 0);
            }
          }
        }
      }
    }
    // parallel exchange: kh=0 -> gates0, kh=1 -> gates1
    {
      float* gx_ = (kh == 0) ? gates0 : gates1;
#pragma unroll
      for (int rb = 0; rb < 4; ++rb)
#pragma unroll
        for (int j = 0; j < 4; ++j)
          gx_[(rb * 16 + rsub + j) * 65 + cg * 16 + fr] = acc[rb][j];
    }
    __syncthreads();
    // epilogue
    float hv[2];
    {
      unsigned gu0 = gxv.x, gu1 = gxv.y, gu2 = gxv.z, gu3 = gxv.w;
#pragma unroll
      for (int j = 0; j < 2; ++j) {
        int hc = hb2 + j;
        float gx0 = j ? bfhi(gu0) : bflo(gu0);
        float gx1 = j ? bfhi(gu1) : bflo(gu1);
        float gx2 = j ? bfhi(gu2) : bflo(gu2);
        float gx3 = j ? bfhi(gu3) : bflo(gu3);
        float pi = gates0[erow * 65 + hc]      + gates1[erow * 65 + hc]      + bI[j] + gx0;
        float pf = gates0[erow * 65 + 16 + hc] + gates1[erow * 65 + 16 + hc] + bF[j] + gx1;
        float po = gates0[erow * 65 + 32 + hc] + gates1[erow * 65 + 32 + hc] + bO[j] + gx2;
        float pg = gates0[erow * 65 + 48 + hc] + gates1[erow * 65 + 48 + hc] + bG[j] + gx3;
        float ig = 1.f / (1.f + __expf(-pi));
        float fg = 1.f / (1.f + __expf(-pf));
        float og = 1.f / (1.f + __expf(-po));
        float gg = 1.f - 2.f / (1.f + __expf(2.f * pg));  // tanh
        float cn = fg * cr[j] + ig * gg;
        cr[j] = cn;
        hv[j] = og * (1.f - 2.f / (1.f + __expf(2.f * cn)));
      }
    }
    if (t < T_DIM - 1) {  // store h_t bf16-pair into slot t%3, swizzled
      int hcg = cb * 16 + hb2;
      int kc2 = hcg >> 7, kp = hcg & 127;
      unsigned byte = ((unsigned)(erow * 256 + kp * 2)) ^ ((unsigned)((erow & 7) << 4));
      unsigned pk = (unsigned)f2bf(hv[0]) | ((unsigned)f2bf(hv[1]) << 16);
      unsigned int* hd = (unsigned int*)(hring + (size_t)(t % 3) * 524288 +
                                         (size_t)(mb * 8 + kc2) * BLK + byte);
      __hip_atomic_store(hd, pk, __ATOMIC_RELAXED, __HIP_MEMORY_SCOPE_AGENT);
    }
    WAITVM(0);        // per-wave: all h stores drained before barrier
    __syncthreads();  // all waves' stores drained; gates reads complete
    if (tid == 0 && t < T_DIM - 1)  // ONE release store to own slot (no RMW)
      __hip_atomic_store(&flags[mb * 64 + cb], (unsigned)(t + 1),
                         __ATOMIC_RELEASE, __HIP_MEMORY_SCOPE_AGENT);
    if (t == T_DIM - 1) {
      *(float2*)(out + gidx) = make_float2(hv[0], hv[1]);
      *(float2*)(out + (size_t)B_DIM * HID_DIM + gidx) = make_float2(cr[0], cr[1]);
    }
  }
  if (t0 + WINT < T_DIM) *(float2*)(cst + gidx) = make_float2(cr[0], cr[1]);
}

extern "C" void kernel_launch(void* const* d_in, const int* in_sizes, int n_in,
                              void* d_out, int out_size, void* d_ws, size_t ws_size,
                              hipStream_t stream) {
  (void)in_sizes; (void)n_in; (void)out_size;
  const float* x   = (const float*)d_in[0];
  const float* Wf_ = (const float*)d_in[1];
  const float* bf_ = (const float*)d_in[2];
  const float* Wi_ = (const float*)d_in[3];
  const float* bi_ = (const float*)d_in[4];
  const float* Wo_ = (const float*)d_in[5];
  const float* bo_ = (const float*)d_in[6];
  const float* Wc_ = (const float*)d_in[7];
  const float* bc_ = (const float*)d_in[8];
  float* out = (float*)d_out;
  unsigned char* ws = (unsigned char*)d_ws;

  unsigned char* Wp = ws;
  size_t off = 16777216;
  float* bp = (float*)(ws + off);                    off += 16384;
  unsigned int* flags = (unsigned int*)(ws + off);   off += 8192;
  unsigned int* consCnt = (unsigned int*)(ws + off); off += 8192;  // unused
  (void)consCnt;
  unsigned char* hring = ws + off;                   off += 3 * 524288;
  float* cst = (float*)(ws + off);                   off += 1048576;
  unsigned char* xpw = ws + off;                     off += (size_t)2048 * BLK;   // 33.5 MB
  unsigned char* gxw = ws + off;                     off += (size_t)WINT * 256 * 8192;  // 134 MB
  if (ws_size < off) return;  // proven available

  prep_pack_w<<<1024, 256, 0, stream>>>(Wi_, Wf_, Wo_, Wc_, Wp);
  prep_bias<<<16, 256, 0, stream>>>(bi_, bf_, bo_, bc_, bp);
  hipMemsetAsync(flags, 0, 16384, stream);

  hipFuncSetAttribute((const void*)bulk_gx,
                      hipFuncAttributeMaxDynamicSharedMemorySize, 65536);
  hipFuncSetAttribute((const void*)lstm_seq,
                      hipFuncAttributeMaxDynamicSharedMemorySize, 131072);

  for (int t0 = 0; t0 < T_DIM; t0 += WINT) {
    prep_pack_x_win<<<2048, 256, 0, stream>>>(x, xpw, t0);
    bulk_gx<<<1024, 512, 65536, stream>>>(xpw, Wp, gxw);
    const unsigned char* a_gx = gxw;
    const unsigned char* a_wp = Wp;
    const float* a_bp = bp;
    unsigned char* a_hr = hring;
    unsigned int* a_fl = flags;
    float* a_cs = cst;
    float* a_out = out;
    int a_t0 = t0;
    void* args[] = {&a_gx, &a_wp, &a_bp, &a_hr, &a_fl, &a_cs, &a_out, &a_t0};
    hipLaunchCooperativeKernel((const void*)lstm_seq, dim3(256), dim3(512),
                               args, 131072u, stream);
  }
}